// Round 1
// baseline (52922.479 us; speedup 1.0000x reference)
//
#include <hip/hip_runtime.h>
#include <math.h>
#include <stdint.h>
#include <limits.h>

#define VSZ 50257
#define ESZ 256
#define HSZ 1024
#define BSZ 64
#define TSZ 80
#define GC  4096  // 4*H gate columns

typedef unsigned int u32;

// ---------------- Threefry-2x32 (JAX exact) ----------------
__device__ __forceinline__ void tf2x32(u32 k0, u32 k1, u32& x0, u32& x1) {
  u32 ks2 = k0 ^ k1 ^ 0x1BD11BDAu;
  x0 += k0; x1 += k1;
#define RND(r) { x0 += x1; x1 = (x1 << r) | (x1 >> (32 - r)); x1 ^= x0; }
  RND(13) RND(15) RND(26) RND(6)
  x0 += k1; x1 += ks2 + 1u;
  RND(17) RND(29) RND(16) RND(24)
  x0 += ks2; x1 += k0 + 2u;
  RND(13) RND(15) RND(26) RND(6)
  x0 += k0; x1 += k1 + 3u;
  RND(17) RND(29) RND(16) RND(24)
  x0 += k1; x1 += ks2 + 4u;
  RND(13) RND(15) RND(26) RND(6)
  x0 += ks2; x1 += k0 + 5u;
#undef RND
}

__device__ __forceinline__ double dsig(double x) { return 0.5 + 0.5 * tanh(0.5 * x); }

// sorted-desc top5 insert; ties -> lower index first (matches lax.top_k)
__device__ __forceinline__ void ins5(double v, int i, double* tv, int* ti) {
  bool beat4 = (v > tv[4]) || (v == tv[4] && i < ti[4]);
  if (!beat4) return;
  tv[4] = v; ti[4] = i;
#pragma unroll
  for (int p = 4; p > 0; --p) {
    bool sw = (tv[p] > tv[p-1]) || (tv[p] == tv[p-1] && ti[p] < ti[p-1]);
    double a0 = sw ? tv[p] : tv[p-1]; double a1 = sw ? tv[p-1] : tv[p];
    tv[p-1] = a0; tv[p] = a1;
    int b0 = sw ? ti[p] : ti[p-1]; int b1 = sw ? ti[p-1] : ti[p];
    ti[p-1] = b0; ti[p] = b1;
  }
}

// -------- RNG: partitionable threefry. keys[t] = tf((0,42),(0,t)) --------
__global__ __launch_bounds__(128) void k_rng_split(u32* __restrict__ so) {
  int t = threadIdx.x;
  if (t < TSZ) {
    u32 x0 = 0u, x1 = (u32)t;
    tf2x32(0u, 42u, x0, x1);
    so[2*t] = x0; so[2*t+1] = x1;
  }
}

// gumbel[t][m], m = b*5+k in [0,320): bits = x0^x1 of tf(key_t,(0,m))
__global__ __launch_bounds__(256) void k_gumbel(const u32* __restrict__ so, double* __restrict__ gum) {
  int idx = blockIdx.x * 256 + threadIdx.x;
  if (idx >= TSZ * 320) return;
  int t = idx / 320, m = idx % 320;
  u32 x0 = 0u, x1 = (u32)m;
  tf2x32(so[2*t], so[2*t+1], x0, x1);
  u32 bits = x0 ^ x1;
  const float TINY = 1.17549435082228750797e-38f;  // 2^-126
  float f = __uint_as_float((bits >> 9) | 0x3f800000u) - 1.0f; // [0,1), 23 bits
  float u = f + TINY;                 // jax: floats*(1-tiny)+tiny with (1-tiny)==1 in f32
  u = fmaxf(TINY, u);
  gum[idx] = -log(-log((double)u));
}

// -------- time encode stage 1: tp1T[hcol][b] = tanh(sin*w1[0,h]+cos*w1[1,h]+b1) --------
__global__ __launch_bounds__(256) void k_time1(const float* __restrict__ hours, const float* __restrict__ w1,
                                               const float* __restrict__ bb1, double* __restrict__ tp1T) {
  int idx = blockIdx.x * 256 + threadIdx.x;  // 64*1024
  int b = idx & 63, hcol = idx >> 6;
  const float TPO = (float)(2.0 * 3.14159265358979323846 / 24.0); // == np.float32(2pi/24)
  float af = hours[b] * TPO;                  // f32 product like jax
  double a = (double)af;
  double sv = sin(a), cv = cos(a);
  double vv = tanh(sv * (double)w1[hcol] + cv * (double)w1[HSZ + hcol] + (double)bb1[hcol]);
  tp1T[(size_t)hcol * 64 + b] = vv;
}

// -------- generic split-K gemm partials: part[s][b][j] (j over 4096 cols) --------
// thread = column j; acc over all 64 batches; X is [k][b] f64 (uniform/scalar loads)
__global__ __launch_bounds__(256) void k_gemm(const double* __restrict__ XTa, const float* __restrict__ Wa,
                                              int Ka, int Sa,
                                              const double* __restrict__ XTb, const float* __restrict__ Wb,
                                              int Kb, int Sb,
                                              double* __restrict__ part) {
  int j = blockIdx.x * 256 + threadIdx.x;
  if (j >= GC) return;
  int s = blockIdx.y;
  const double* XT; const float* W; int k0, kc;
  if (s < Sa) { kc = Ka / Sa; XT = XTa; W = Wa; k0 = s * kc; }
  else        { kc = Kb / Sb; XT = XTb; W = Wb; k0 = (s - Sa) * kc; }
  double acc[BSZ];
#pragma unroll
  for (int b = 0; b < BSZ; ++b) acc[b] = 0.0;
  const float* wp = W + (size_t)k0 * GC + j;
  const double* xp = XT + (size_t)k0 * 64;
  for (int k = 0; k < kc; ++k) {
    double wv = (double)wp[0]; wp += GC;
#pragma unroll
    for (int b = 0; b < BSZ; ++b) acc[b] = fma(wv, xp[b], acc[b]);
    xp += 64;
  }
  double* o = part + ((size_t)s * 64) * GC + j;
#pragma unroll
  for (int b = 0; b < BSZ; ++b) o[(size_t)b * GC] = acc[b];
}

// -------- time encode stage 2 reduce: route tp2 -> h0,c0,h1,c1 --------
__global__ __launch_bounds__(256) void k_t2r(const double* __restrict__ part, const float* __restrict__ b2,
                                             double* __restrict__ h0T, double* __restrict__ c0,
                                             double* __restrict__ h1T, double* __restrict__ c1) {
  int b = blockIdx.y;
  int j = blockIdx.x * 256 + threadIdx.x;  // [0,4096)
  double acc = (double)b2[j];
  for (int s = 0; s < 8; ++s) acc += part[((size_t)s * 64 + b) * GC + j];
  int l = j >> 11, half = (j >> 10) & 1, hcol = j & 1023;
  if (half == 0) (l ? h1T : h0T)[(size_t)hcol * 64 + b] = acc;
  else           (l ? c1 : c0)[(size_t)b * HSZ + hcol] = acc;
}

// -------- LSTM cell: sum partials + bias, gate order i,f,g,o --------
__global__ __launch_bounds__(256) void k_cell(const double* __restrict__ part, int S,
                                              const float* __restrict__ bias,
                                              double* __restrict__ c, double* __restrict__ hT) {
  int b = blockIdx.y;
  int hcol = blockIdx.x * 256 + threadIdx.x;  // [0,1024)
  double gi = (double)bias[hcol];
  double gf = (double)bias[1024 + hcol];
  double gg = (double)bias[2048 + hcol];
  double go = (double)bias[3072 + hcol];
  for (int s = 0; s < S; ++s) {
    const double* p = part + ((size_t)s * 64 + b) * GC;
    gi += p[hcol]; gf += p[1024 + hcol]; gg += p[2048 + hcol]; go += p[3072 + hcol];
  }
  size_t ci = (size_t)b * HSZ + hcol;
  double cn = dsig(gf) * c[ci] + dsig(gi) * tanh(gg);
  double hn = dsig(go) * tanh(cn);
  c[ci] = cn;
  hT[(size_t)hcol * 64 + b] = hn;
}

// -------- FC partials: logits_part[y][b][v], y = k-half --------
__global__ __launch_bounds__(256) void k_fc(const double* __restrict__ h1T, const float* __restrict__ W,
                                            double* __restrict__ lgt0, double* __restrict__ lgt1) {
  int v = blockIdx.x * 256 + threadIdx.x;
  if (v >= VSZ) return;
  double* o = (blockIdx.y == 0) ? lgt0 : lgt1;
  int k0 = blockIdx.y * 512;
  double acc[BSZ];
#pragma unroll
  for (int b = 0; b < BSZ; ++b) acc[b] = 0.0;
  const float* wp = W + (size_t)k0 * VSZ + v;
  const double* xp = h1T + (size_t)k0 * 64;
  for (int k = 0; k < 512; ++k) {
    double wv = (double)wp[0]; wp += VSZ;
#pragma unroll
    for (int b = 0; b < BSZ; ++b) acc[b] = fma(wv, xp[b], acc[b]);
    xp += 64;
  }
#pragma unroll
  for (int b = 0; b < BSZ; ++b) o[(size_t)b * VSZ + v] = acc[b];
}

// -------- per-(b,chunk) top5 of logits; 16 chunks x 64 b, 1 wave each --------
__global__ __launch_bounds__(64) void k_top1(const double* __restrict__ l0, const double* __restrict__ l1,
                                             const float* __restrict__ fcb,
                                             double* __restrict__ candV, int* __restrict__ candI) {
  int b = blockIdx.y, chunk = blockIdx.x, lane = threadIdx.x;
  const double* r0 = l0 + (size_t)b * VSZ;
  const double* r1 = l1 + (size_t)b * VSZ;
  double tv[5]; int ti[5];
#pragma unroll
  for (int p = 0; p < 5; ++p) { tv[p] = -INFINITY; ti[p] = INT_MAX; }
  int lo = chunk * 3142, hi = lo + 3142; if (hi > VSZ) hi = VSZ;
  for (int i = lo + lane; i < hi; i += 64) {
    double val = (r0[i] + r1[i] + (double)fcb[i]) / 0.75;  // true divide like /TEMP
    ins5(val, i, tv, ti);
  }
  // 5 rounds of wave-argmax; winner pops its head (all static indexing)
  for (int r = 0; r < 5; ++r) {
    double bv = tv[0]; int bi = ti[0];
    for (int off = 1; off < 64; off <<= 1) {
      double ov = __shfl_xor(bv, off, 64);
      int oi = __shfl_xor(bi, off, 64);
      if (ov > bv || (ov == bv && oi < bi)) { bv = ov; bi = oi; }
    }
    if (lane == 0) {
      candV[(chunk * 5 + r) * 64 + b] = bv;
      candI[(chunk * 5 + r) * 64 + b] = bi;
    }
    bool mine = (tv[0] == bv && ti[0] == bi);
    if (mine) {
#pragma unroll
      for (int p = 0; p < 4; ++p) { tv[p] = tv[p+1]; ti[p] = ti[p+1]; }
      tv[4] = -INFINITY; ti[4] = INT_MAX;
    }
  }
}

// -------- final merge + gumbel sample + outputs + next embedding --------
__global__ __launch_bounds__(256) void k_fin(const double* __restrict__ candV, const int* __restrict__ candI,
                                             const double* __restrict__ gum, int t,
                                             const float* __restrict__ embed,
                                             float* __restrict__ out, double* __restrict__ xt0) {
  __shared__ int ltok[BSZ];
  int tid = threadIdx.x;
  if (tid < BSZ) {
    int b = tid;
    double tv[5]; int ti[5];
#pragma unroll
    for (int p = 0; p < 5; ++p) { tv[p] = -INFINITY; ti[p] = INT_MAX; }
    for (int e = 0; e < 80; ++e) ins5(candV[e * 64 + b], candI[e * 64 + b], tv, ti);
    const double* g = gum + (size_t)t * 320 + b * 5;
    double bestv = tv[0] + g[0]; int best = 0;
#pragma unroll
    for (int k2 = 1; k2 < 5; ++k2) { double vv = tv[k2] + g[k2]; if (vv > bestv) { bestv = vv; best = k2; } }
    int nxt = ti[best];
    double m = tv[0];
    double ex[5]; double s = 0.0;
#pragma unroll
    for (int k2 = 0; k2 < 5; ++k2) { ex[k2] = exp(tv[k2] - m); s += ex[k2]; }
    out[b * TSZ + t] = (float)nxt;  // token as float value (mixed-dtype tuple -> f32 buffer)
    float* po = out + BSZ * TSZ + ((size_t)b * TSZ + t) * 5;
#pragma unroll
    for (int k2 = 0; k2 < 5; ++k2) po[k2] = (float)(ex[k2] / s);
    ltok[b] = nxt;
  }
  __syncthreads();
  int k = tid;  // 0..255 = embedding dim
  for (int b = 0; b < BSZ; ++b)
    xt0[(size_t)k * 64 + b] = (double)embed[(size_t)ltok[b] * ESZ + k];
}

// -------- initial embedding of SOS --------
__global__ __launch_bounds__(256) void k_emb0(const float* __restrict__ embed, const int* __restrict__ sos,
                                              double* __restrict__ xt0) {
  int idx = blockIdx.x * 256 + threadIdx.x;  // 256*64
  int b = idx & 63, k = idx >> 6;
  xt0[(size_t)k * 64 + b] = (double)embed[(size_t)sos[0] * ESZ + k];
}

extern "C" void kernel_launch(void* const* d_in, const int* in_sizes, int n_in,
                              void* d_out, int out_size, void* d_ws, size_t ws_size,
                              hipStream_t stream) {
  const float* hours = (const float*)d_in[0];
  const float* tp_w1 = (const float*)d_in[1];
  const float* tp_b1 = (const float*)d_in[2];
  const float* tp_w2 = (const float*)d_in[3];
  const float* tp_b2 = (const float*)d_in[4];
  const float* embed = (const float*)d_in[5];
  const float* w_ih0 = (const float*)d_in[6];
  const float* w_hh0 = (const float*)d_in[7];
  const float* b0    = (const float*)d_in[8];
  const float* w_ih1 = (const float*)d_in[9];
  const float* w_hh1 = (const float*)d_in[10];
  const float* b1    = (const float*)d_in[11];
  const float* fc_w  = (const float*)d_in[12];
  const float* fc_b  = (const float*)d_in[13];
  const int*   sos   = (const int*)d_in[14];
  float* out = (float*)d_out;

  char* w = (char*)d_ws;
  double* part = (double*)w;  w += (size_t)16 * 64 * GC * 8;      // 33.55 MB split-K partials
  double* lgt0 = (double*)w;  w += (size_t)BSZ * VSZ * 8;         // 25.73 MB logits half 0
  double* lgt1 = part;                                            // half 1 reuses part
  double* xt0  = (double*)w;  w += (size_t)ESZ * 64 * 8;
  double* h0T  = (double*)w;  w += (size_t)HSZ * 64 * 8;
  double* h1T  = (double*)w;  w += (size_t)HSZ * 64 * 8;
  double* c0   = (double*)w;  w += (size_t)BSZ * HSZ * 8;
  double* c1   = (double*)w;  w += (size_t)BSZ * HSZ * 8;
  double* tp1T = (double*)w;  w += (size_t)HSZ * 64 * 8;
  double* gum  = (double*)w;  w += (size_t)TSZ * 320 * 8;
  u32*    so   = (u32*)w;     w += 1024;
  double* candV = (double*)w; w += (size_t)80 * 64 * 8;
  int*    candI = (int*)w;    w += (size_t)80 * 64 * 4;

  k_rng_split<<<dim3(1), dim3(128), 0, stream>>>(so);
  k_gumbel<<<dim3(100), dim3(256), 0, stream>>>(so, gum);
  k_time1<<<dim3(256), dim3(256), 0, stream>>>(hours, tp_w1, tp_b1, tp1T);
  k_gemm<<<dim3(16, 8), dim3(256), 0, stream>>>(tp1T, tp_w2, 1024, 8, tp1T, tp_w2, 1024, 8, part);
  k_t2r<<<dim3(16, 64), dim3(256), 0, stream>>>(part, tp_b2, h0T, c0, h1T, c1);
  k_emb0<<<dim3(64), dim3(256), 0, stream>>>(embed, sos, xt0);

  for (int t = 0; t < TSZ; ++t) {
    k_gemm<<<dim3(16, 10), dim3(256), 0, stream>>>(xt0, w_ih0, 256, 2, h0T, w_hh0, 1024, 8, part);
    k_cell<<<dim3(4, 64), dim3(256), 0, stream>>>(part, 10, b0, c0, h0T);
    k_gemm<<<dim3(16, 16), dim3(256), 0, stream>>>(h0T, w_ih1, 1024, 8, h1T, w_hh1, 1024, 8, part);
    k_cell<<<dim3(4, 64), dim3(256), 0, stream>>>(part, 16, b1, c1, h1T);
    k_fc<<<dim3(197, 2), dim3(256), 0, stream>>>(h1T, fc_w, lgt0, lgt1);
    k_top1<<<dim3(16, 64), dim3(64), 0, stream>>>(lgt0, lgt1, fc_b, candV, candI);
    k_fin<<<dim3(1), dim3(256), 0, stream>>>(candV, candI, gum, t, embed, out, xt0);
  }
}